// Round 2
// baseline (216.484 us; speedup 1.0000x reference)
//
#include <hip/hip_runtime.h>

// ModulatedConv2d: B=16, IN=512, OUT=512, STYLE=512, K=3, H=W=32
// out[b,o] = scale[b,o] * conv2d(x[b,i]*s[b,i], W[o,i])   (shared weights!)
//   s[b,i]     = style[b,:]·aff_w[i,:]*aff_scale + aff_b[i] + 1
//   wsq[o,i]   = sum_e W[o,i,e]^2   (fp32)
//   scale[b,o] = w_scale * rsqrt(w_scale^2 * sum_i s^2*wsq + 1e-8)  [conv prologue]
// Conv as implicit GEMM (bf16 MFMA, fp32 accum): M=512 out-ch, N=1024 px/batch,
// K = 9 offsets x 512 ch. x staged as zero-padded NHWC bf16 -> no masking.
// LDS tiles XOR-swizzled (chunk c of row r at slot c^((r>>1)&3)) so fragment
// ds_read_b128s are 2-way-max on banks (free) instead of 8-way. [R1: 9.4M confl]

#define BATCH   16
#define CIN     512
#define COUT    512
#define IMG     32
#define PAD_IMG 34

static constexpr float AFF_SCALE = 0.044194173824159216f;  // 1/sqrt(512)
static constexpr float W_SCALE   = 0.014731391274719739f;  // 1/sqrt(512*9)

typedef __bf16 bf16x8 __attribute__((ext_vector_type(8)));
typedef float  f32x4  __attribute__((ext_vector_type(4)));

__device__ inline unsigned short f2bf(float f) {
    union { float f; unsigned int u; } v; v.f = f;
    unsigned int u = v.u;
    unsigned int r = (u + 0x7FFFu + ((u >> 16) & 1u)) >> 16;
    return (unsigned short)r;
}

__device__ inline float waveReduceSum(float v) {
    #pragma unroll
    for (int off = 32; off > 0; off >>= 1) v += __shfl_xor(v, off, 64);
    return v;
}

// ---- kernel 1: fused prep ----
// blocks 0..1023:   repack_w  (wsq[o,i], w_t[e][o][i] bf16)
// blocks 1024..3071: compute_s (s[b,i] and s^2)
__global__ void prep1(const float* __restrict__ cw,
                      const float* __restrict__ style,
                      const float* __restrict__ aw,
                      const float* __restrict__ ab,
                      unsigned short* __restrict__ w_t,
                      float* __restrict__ wsq,
                      float* __restrict__ s_out,
                      float* __restrict__ ssq_out) {
    const int tid = threadIdx.x;
    if (blockIdx.x < 1024) {
        // repack: this block covers 256 consecutive (o,i) pairs = 2304 floats
        __shared__ float wl[2304];
        const float* src = cw + (size_t)blockIdx.x * 2304;
        for (int j = tid; j < 2304; j += 256) wl[j] = src[j];
        __syncthreads();
        const int idx = blockIdx.x * 256 + tid;       // o*512 + i
        const int base = tid * 9;
        float acc = 0.f;
        #pragma unroll
        for (int e = 0; e < 9; ++e) {
            float v = wl[base + e];
            acc += v * v;
            w_t[e * (COUT * CIN) + idx] = f2bf(v);
        }
        wsq[idx] = acc;
    } else {
        const int q = blockIdx.x - 1024;              // 0..2047
        const int b = q >> 7;
        const int i = (q & 127) * 4 + (tid >> 6);
        const int lane = tid & 63;
        float sum = 0.f;
        #pragma unroll
        for (int k = 0; k < 512; k += 64)
            sum += style[b * 512 + k + lane] * aw[i * 512 + k + lane];
        sum = waveReduceSum(sum);
        if (lane == 0) {
            float s = sum * AFF_SCALE + ab[i] + 1.0f;
            s_out[b * 512 + i] = s;
            ssq_out[b * 512 + i] = s * s;
        }
    }
}

// ---- kernel 2: x_pad[b][hh][ww][c] = bf16(x[b][c][hh-1][ww-1]*s[b][c]), 0 border
// grid (CIN/64, 34, BATCH), block 256. LDS transpose 64ch x 32w.
__global__ void build_xpad(const float* __restrict__ x,
                           const float* __restrict__ s_in,
                           unsigned short* __restrict__ xpad) {
    const int c0 = blockIdx.x * 64;
    const int hh = blockIdx.y;
    const int b  = blockIdx.z;
    const int tid = threadIdx.x;
    unsigned short* rowbase = xpad + (((size_t)b * PAD_IMG + hh) * PAD_IMG) * 512;

    if (hh == 0 || hh == PAD_IMG - 1) {
        for (int j = tid; j < 34 * 32; j += 256) {
            int ww = j >> 5, cp = (j & 31) * 2;
            *(unsigned int*)(rowbase + (size_t)ww * 512 + c0 + cp) = 0u;
        }
        return;
    }

    __shared__ float t[64][33];
    const int h = hh - 1;
    {
        const int wx = tid & 31;
        const int cb = (tid >> 5) * 8;
        const float* xb = x + (((size_t)b * 512 + c0 + cb) * IMG + h) * IMG + wx;
        #pragma unroll
        for (int j = 0; j < 8; ++j)
            t[cb + j][wx] = xb[(size_t)j * (IMG * IMG)] * s_in[b * 512 + c0 + cb + j];
    }
    __syncthreads();
    {
        const int p  = tid >> 3;          // 0..31 image col
        const int cc = (tid & 7) * 8;     // channel offset
        unsigned short* dst = rowbase + (size_t)(p + 1) * 512 + c0 + cc;
        uint4 pk;
        pk.x = (unsigned)f2bf(t[cc + 0][p]) | ((unsigned)f2bf(t[cc + 1][p]) << 16);
        pk.y = (unsigned)f2bf(t[cc + 2][p]) | ((unsigned)f2bf(t[cc + 3][p]) << 16);
        pk.z = (unsigned)f2bf(t[cc + 4][p]) | ((unsigned)f2bf(t[cc + 5][p]) << 16);
        pk.w = (unsigned)f2bf(t[cc + 6][p]) | ((unsigned)f2bf(t[cc + 7][p]) << 16);
        *(uint4*)dst = pk;
    }
    if (tid < 64) {
        int ww = (tid >> 5) ? (PAD_IMG - 1) : 0;
        int cp = (tid & 31) * 2;
        *(unsigned int*)(rowbase + (size_t)ww * 512 + c0 + cp) = 0u;
    }
}

// ---- kernel 3: implicit-GEMM conv, 128x128 tile, bf16 MFMA, swizzled LDS ----
// grid (COUT/128, 1024/128, BATCH) = (4,8,16), block 256 (4 waves, 64x64 each)
__global__ __launch_bounds__(256, 2) void conv_mfma(
    const unsigned short* __restrict__ wt,    // [9][512][512] bf16
    const unsigned short* __restrict__ xpad,  // [16][34][34][512] bf16
    const float* __restrict__ wsq,            // [512][512]
    const float* __restrict__ ssq,            // [16][512]
    float* __restrict__ out)                  // [16][512][32][32]
{
    __shared__ unsigned short Alds[128 * 32];
    __shared__ unsigned short Blds[128 * 32];
    __shared__ float sclds[128];

    const int tid = threadIdx.x;
    const int b   = blockIdx.z;
    const int m0  = blockIdx.x * 128;
    const int h0  = blockIdx.y * 4;

    // prologue: scale[b, m0+ol] = W_SCALE*rsqrt(W_SCALE^2*sum_i ssq*wsq + 1e-8)
    {
        const int ol   = tid >> 1;
        const int half = tid & 1;
        const f32x4* w4 = (const f32x4*)(wsq + (size_t)(m0 + ol) * 512 + half * 256);
        const f32x4* s4 = (const f32x4*)(ssq + b * 512 + half * 256);
        float sum = 0.f;
        #pragma unroll 4
        for (int i = 0; i < 64; ++i) {
            f32x4 a = w4[i], c = s4[i];
            sum += a.x * c.x + a.y * c.y + a.z * c.z + a.w * c.w;
        }
        sum += __shfl_xor(sum, 1, 64);
        if (half == 0)
            sclds[ol] = W_SCALE * rsqrtf(W_SCALE * W_SCALE * sum + 1e-8f);
        // visibility to epilogue readers: covered by the K-loop barriers
    }

    const int wid  = tid >> 6;
    const int lane = tid & 63;
    const int wm = wid & 1, wn = wid >> 1;

    const f32x4 vzero = {0.f, 0.f, 0.f, 0.f};
    f32x4 acc[4][4];
    #pragma unroll
    for (int i = 0; i < 4; ++i)
        #pragma unroll
        for (int j = 0; j < 4; ++j) acc[i][j] = vzero;

    // staging: thread's forced LDS slot f = r*256+tid holds (row=f>>2, pos=f&3);
    // fetch global chunk c = pos ^ ((row>>1)&3)  (swizzle; permutes within 64B)
    int aOff[2], bOff[2], ldsBase[2];
    #pragma unroll
    for (int r = 0; r < 2; ++r) {
        int f   = r * 256 + tid;
        int row = f >> 2;
        int pos = f & 3;
        int c   = pos ^ ((row >> 1) & 3);
        aOff[r] = row * 512 + c * 8;
        bOff[r] = ((row >> 5) * PAD_IMG + (row & 31)) * 512 + c * 8;
        ldsBase[r] = (r * 256 + wid * 64) * 8;     // dest: wave-uniform + lane*16B
    }

    // fragment read addresses (shorts), swizzled: row R, chunk k at
    // R*32 + (k ^ ((R>>1)&3))*8 ; (R>>1)&3 == ((lane&15)>>1)&3 since base%16==0
    const int rl   = lane & 15;
    const int kch  = lane >> 4;
    const int swz  = (kch ^ ((rl >> 1) & 3)) * 8;
    const int arow = (wm * 64 + rl) * 32 + swz;
    const int brow = (wn * 64 + rl) * 32 + swz;

    for (int e = 0; e < 9; ++e) {
        const int kh = e / 3, kw = e % 3;
        const unsigned short* Abase = wt + (size_t)e * (COUT * CIN) + (size_t)m0 * 512;
        const unsigned short* Bbase =
            xpad + (((size_t)b * PAD_IMG + h0 + kh) * PAD_IMG + kw) * 512;
        for (int kc = 0; kc < 512; kc += 32) {
            __syncthreads();
            #pragma unroll
            for (int r = 0; r < 2; ++r)
                __builtin_amdgcn_global_load_lds(
                    (const __attribute__((address_space(1))) void*)(Abase + aOff[r] + kc),
                    (__attribute__((address_space(3))) void*)(&Alds[ldsBase[r]]),
                    16, 0, 0);
            #pragma unroll
            for (int r = 0; r < 2; ++r)
                __builtin_amdgcn_global_load_lds(
                    (const __attribute__((address_space(1))) void*)(Bbase + bOff[r] + kc),
                    (__attribute__((address_space(3))) void*)(&Blds[ldsBase[r]]),
                    16, 0, 0);
            __syncthreads();

            bf16x8 af[4], bfr[4];
            #pragma unroll
            for (int mi = 0; mi < 4; ++mi)
                af[mi] = *(const bf16x8*)(&Alds[arow + mi * 16 * 32]);
            #pragma unroll
            for (int ni = 0; ni < 4; ++ni)
                bfr[ni] = *(const bf16x8*)(&Blds[brow + ni * 16 * 32]);
            #pragma unroll
            for (int mi = 0; mi < 4; ++mi)
                #pragma unroll
                for (int ni = 0; ni < 4; ++ni)
                    acc[mi][ni] = __builtin_amdgcn_mfma_f32_16x16x32_bf16(
                        af[mi], bfr[ni], acc[mi][ni], 0, 0, 0);
        }
    }

    // epilogue: C[m][n] layout col=lane&15, row=(lane>>4)*4+reg  [m89-verified]
    const int colp = lane & 15;
    const int rowq = (lane >> 4) * 4;
    const int p0 = h0 * 32;
    #pragma unroll
    for (int mi = 0; mi < 4; ++mi) {
        #pragma unroll
        for (int ni = 0; ni < 4; ++ni) {
            const int p = p0 + wn * 64 + ni * 16 + colp;
            #pragma unroll
            for (int r2 = 0; r2 < 4; ++r2) {
                const int ol = wm * 64 + mi * 16 + rowq + r2;
                out[(((size_t)b * 512 + m0 + ol) << 10) + p] =
                    acc[mi][ni][r2] * sclds[ol];
            }
        }
    }
}

extern "C" void kernel_launch(void* const* d_in, const int* in_sizes, int n_in,
                              void* d_out, int out_size, void* d_ws, size_t ws_size,
                              hipStream_t stream) {
    const float* x     = (const float*)d_in[0];  // [16,512,32,32]
    const float* style = (const float*)d_in[1];  // [16,512]
    const float* aw    = (const float*)d_in[2];  // [512,512]
    const float* ab    = (const float*)d_in[3];  // [512]
    const float* cw    = (const float*)d_in[4];  // [512,512,3,3]
    float* out = (float*)d_out;

    char* ws = (char*)d_ws;
    float* s_buf          = (float*)(ws);                      //  32 KB
    float* ssq            = (float*)(ws + 32768);              //  32 KB
    float* wsq            = (float*)(ws + 65536);              //   1 MB
    unsigned short* w_t   = (unsigned short*)(ws + 1114112);   // 4.5 MB bf16
    unsigned short* x_pad = (unsigned short*)(ws + 5832704);   // 18.9 MB bf16
    // total ws need: 24,772,608 B (same as round 1)

    prep1<<<dim3(3072), 256, 0, stream>>>(cw, style, aw, ab, w_t, wsq, s_buf, ssq);
    build_xpad<<<dim3(8, 34, 16), 256, 0, stream>>>(x, s_buf, x_pad);
    conv_mfma<<<dim3(4, 8, 16), 256, 0, stream>>>(w_t, x_pad, wsq, ssq, out);
}

// Round 3
// 193.338 us; speedup vs baseline: 1.1197x; 1.1197x over previous
//
#include <hip/hip_runtime.h>

// ModulatedConv2d: B=16, IN=512, OUT=512, STYLE=512, K=3, H=W=32
// out[b,o] = scale[b,o] * conv2d(x[b,i]*s[b,i], W[o,i])   (shared weights!)
// Conv as implicit GEMM (bf16 MFMA, fp32 accum): M=512 out-ch, N=1024 px/batch,
// K = 9 offsets x 512 ch. x staged as zero-padded NHWC bf16 -> no masking.
//
// R2 lesson: LDS bank conflicts (9.4M cyc) are fully hidden under the vmcnt
// drain -- swizzling them away + in-conv scale prologue cost +21us. Reverted.
// R3: XCD-aware grid swizzle. R1/R2 FETCH_SIZE=300MB vs ~25MB unique input:
// blocks sharing B-tiles/weights were spread across all 8 XCD L2s. Now
// id&7 -> XCD owns 16 (h,b)-pairs x 4 m-blocks; per-XCD L2 set ~8MB.

#define BATCH   16
#define CIN     512
#define COUT    512
#define IMG     32
#define PAD_IMG 34

static constexpr float AFF_SCALE = 0.044194173824159216f;  // 1/sqrt(512)
static constexpr float W_SCALE   = 0.014731391274719739f;  // 1/sqrt(512*9)

typedef __bf16 bf16x8 __attribute__((ext_vector_type(8)));
typedef float  f32x4  __attribute__((ext_vector_type(4)));

__device__ inline unsigned short f2bf(float f) {
    union { float f; unsigned int u; } v; v.f = f;
    unsigned int u = v.u;
    unsigned int r = (u + 0x7FFFu + ((u >> 16) & 1u)) >> 16;
    return (unsigned short)r;
}

__device__ inline float waveReduceSum(float v) {
    #pragma unroll
    for (int off = 32; off > 0; off >>= 1) v += __shfl_xor(v, off, 64);
    return v;
}

// ---- kernel 1: fused prep ----
// blocks 0..1023:   repack_w  (wsq[o,i], w_t[e][o][i] bf16)
// blocks 1024..3071: compute_s (s[b,i])
__global__ void prep1(const float* __restrict__ cw,
                      const float* __restrict__ style,
                      const float* __restrict__ aw,
                      const float* __restrict__ ab,
                      unsigned short* __restrict__ w_t,
                      float* __restrict__ wsq,
                      float* __restrict__ s_out) {
    const int tid = threadIdx.x;
    if (blockIdx.x < 1024) {
        __shared__ float wl[2304];
        const float* src = cw + (size_t)blockIdx.x * 2304;
        for (int j = tid; j < 2304; j += 256) wl[j] = src[j];
        __syncthreads();
        const int idx = blockIdx.x * 256 + tid;       // o*512 + i
        const int base = tid * 9;
        float acc = 0.f;
        #pragma unroll
        for (int e = 0; e < 9; ++e) {
            float v = wl[base + e];
            acc += v * v;
            w_t[e * (COUT * CIN) + idx] = f2bf(v);
        }
        wsq[idx] = acc;
    } else {
        const int q = blockIdx.x - 1024;              // 0..2047
        const int b = q >> 7;
        const int i = (q & 127) * 4 + (tid >> 6);
        const int lane = tid & 63;
        float sum = 0.f;
        #pragma unroll
        for (int k = 0; k < 512; k += 64)
            sum += style[b * 512 + k + lane] * aw[i * 512 + k + lane];
        sum = waveReduceSum(sum);
        if (lane == 0)
            s_out[b * 512 + i] = sum * AFF_SCALE + ab[i] + 1.0f;
    }
}

// ---- kernel 2: scale[b,o] ---- grid (COUT/4, BATCH), one wave per (b,o)
__global__ void compute_scale(const float* __restrict__ s_in,
                              const float* __restrict__ wsq,
                              float* __restrict__ scl) {
    const int o = blockIdx.x * 4 + (threadIdx.x >> 6);
    const int b = blockIdx.y;
    const int lane = threadIdx.x & 63;
    float sum = 0.f;
    #pragma unroll
    for (int i = 0; i < 512; i += 64) {
        float sv = s_in[b * 512 + i + lane];
        sum += sv * sv * wsq[o * 512 + i + lane];
    }
    sum = waveReduceSum(sum);
    if (lane == 0)
        scl[b * 512 + o] = W_SCALE * rsqrtf(W_SCALE * W_SCALE * sum + 1e-8f);
}

// ---- kernel 3: x_pad[b][hh][ww][c] = bf16(x[b][c][hh-1][ww-1]*s[b][c]), 0 border
__global__ void build_xpad(const float* __restrict__ x,
                           const float* __restrict__ s_in,
                           unsigned short* __restrict__ xpad) {
    const int c0 = blockIdx.x * 64;
    const int hh = blockIdx.y;
    const int b  = blockIdx.z;
    const int tid = threadIdx.x;
    unsigned short* rowbase = xpad + (((size_t)b * PAD_IMG + hh) * PAD_IMG) * 512;

    if (hh == 0 || hh == PAD_IMG - 1) {
        for (int j = tid; j < 34 * 32; j += 256) {
            int ww = j >> 5, cp = (j & 31) * 2;
            *(unsigned int*)(rowbase + (size_t)ww * 512 + c0 + cp) = 0u;
        }
        return;
    }

    __shared__ float t[64][33];
    const int h = hh - 1;
    {
        const int wx = tid & 31;
        const int cb = (tid >> 5) * 8;
        const float* xb = x + (((size_t)b * 512 + c0 + cb) * IMG + h) * IMG + wx;
        #pragma unroll
        for (int j = 0; j < 8; ++j)
            t[cb + j][wx] = xb[(size_t)j * (IMG * IMG)] * s_in[b * 512 + c0 + cb + j];
    }
    __syncthreads();
    {
        const int p  = tid >> 3;
        const int cc = (tid & 7) * 8;
        unsigned short* dst = rowbase + (size_t)(p + 1) * 512 + c0 + cc;
        uint4 pk;
        pk.x = (unsigned)f2bf(t[cc + 0][p]) | ((unsigned)f2bf(t[cc + 1][p]) << 16);
        pk.y = (unsigned)f2bf(t[cc + 2][p]) | ((unsigned)f2bf(t[cc + 3][p]) << 16);
        pk.z = (unsigned)f2bf(t[cc + 4][p]) | ((unsigned)f2bf(t[cc + 5][p]) << 16);
        pk.w = (unsigned)f2bf(t[cc + 6][p]) | ((unsigned)f2bf(t[cc + 7][p]) << 16);
        *(uint4*)dst = pk;
    }
    if (tid < 64) {
        int ww = (tid >> 5) ? (PAD_IMG - 1) : 0;
        int cp = (tid & 31) * 2;
        *(unsigned int*)(rowbase + (size_t)ww * 512 + c0 + cp) = 0u;
    }
}

// ---- kernel 4: implicit-GEMM conv, 128x128 tile, bf16 MFMA ----
// grid 512 (1-D, XCD-swizzled), block 256 (4 waves, 64x64 each)
__global__ __launch_bounds__(256, 2) void conv_mfma(
    const unsigned short* __restrict__ wt,    // [9][512][512] bf16
    const unsigned short* __restrict__ xpad,  // [16][34][34][512] bf16
    const float* __restrict__ scl,            // [16][512]
    float* __restrict__ out)                  // [16][512][32][32]
{
    __shared__ unsigned short Alds[128 * 32];
    __shared__ unsigned short Blds[128 * 32];
    __shared__ float sclds[128];

    const int tid = threadIdx.x;
    // XCD swizzle: id&7 -> XCD (dispatch round-robin). Each XCD gets
    // 16 (h,b)-pairs x 4 m-blocks = 64 co-resident blocks; B rows + the
    // streaming A tile then live in that XCD's own L2.
    const int id    = blockIdx.x;
    const int xcd   = id & 7;
    const int local = id >> 3;            // 0..63
    const int gp    = xcd * 16 + (local >> 2);   // 0..127  (h,b) pair
    const int m0  = (local & 3) * 128;
    const int h0  = (gp & 7) * 4;
    const int b   = gp >> 3;

    if (tid < 128) sclds[tid] = scl[b * 512 + m0 + tid];

    const int wid  = tid >> 6;
    const int lane = tid & 63;
    const int wm = wid & 1, wn = wid >> 1;

    const f32x4 vzero = {0.f, 0.f, 0.f, 0.f};
    f32x4 acc[4][4];
    #pragma unroll
    for (int i = 0; i < 4; ++i)
        #pragma unroll
        for (int j = 0; j < 4; ++j) acc[i][j] = vzero;

    int aOff[2], bOff[2], ldsBase[2];
    #pragma unroll
    for (int r = 0; r < 2; ++r) {
        int f   = r * 256 + tid;       // flat 16B-chunk id
        int row = f >> 2;              // tile row (0..127)
        int col = (f & 3) * 8;         // bf16 offset within 32-wide K
        aOff[r] = row * 512 + col;
        bOff[r] = ((row >> 5) * PAD_IMG + (row & 31)) * 512 + col;
        ldsBase[r] = (r * 256 + wid * 64) * 8;     // wave-uniform dest
    }

    const int arow = (wm * 64 + (lane & 15)) * 32 + (lane >> 4) * 8;
    const int brow = (wn * 64 + (lane & 15)) * 32 + (lane >> 4) * 8;

    for (int e = 0; e < 9; ++e) {
        const int kh = e / 3, kw = e % 3;
        const unsigned short* Abase = wt + (size_t)e * (COUT * CIN) + (size_t)m0 * 512;
        const unsigned short* Bbase =
            xpad + (((size_t)b * PAD_IMG + h0 + kh) * PAD_IMG + kw) * 512;
        for (int kc = 0; kc < 512; kc += 32) {
            __syncthreads();
            #pragma unroll
            for (int r = 0; r < 2; ++r)
                __builtin_amdgcn_global_load_lds(
                    (const __attribute__((address_space(1))) void*)(Abase + aOff[r] + kc),
                    (__attribute__((address_space(3))) void*)(&Alds[ldsBase[r]]),
                    16, 0, 0);
            #pragma unroll
            for (int r = 0; r < 2; ++r)
                __builtin_amdgcn_global_load_lds(
                    (const __attribute__((address_space(1))) void*)(Bbase + bOff[r] + kc),
                    (__attribute__((address_space(3))) void*)(&Blds[ldsBase[r]]),
                    16, 0, 0);
            __syncthreads();

            bf16x8 af[4], bfr[4];
            #pragma unroll
            for (int mi = 0; mi < 4; ++mi)
                af[mi] = *(const bf16x8*)(&Alds[arow + mi * 16 * 32]);
            #pragma unroll
            for (int ni = 0; ni < 4; ++ni)
                bfr[ni] = *(const bf16x8*)(&Blds[brow + ni * 16 * 32]);
            #pragma unroll
            for (int mi = 0; mi < 4; ++mi)
                #pragma unroll
                for (int ni = 0; ni < 4; ++ni)
                    acc[mi][ni] = __builtin_amdgcn_mfma_f32_16x16x32_bf16(
                        af[mi], bfr[ni], acc[mi][ni], 0, 0, 0);
        }
    }

    // epilogue: C[m][n] layout col=lane&15, row=(lane>>4)*4+reg  [m89-verified]
    const int colp = lane & 15;
    const int rowq = (lane >> 4) * 4;
    const int p0 = h0 * 32;
    #pragma unroll
    for (int mi = 0; mi < 4; ++mi) {
        #pragma unroll
        for (int ni = 0; ni < 4; ++ni) {
            const int p = p0 + wn * 64 + ni * 16 + colp;
            #pragma unroll
            for (int r2 = 0; r2 < 4; ++r2) {
                const int ol = wm * 64 + mi * 16 + rowq + r2;
                out[(((size_t)b * 512 + m0 + ol) << 10) + p] =
                    acc[mi][ni][r2] * sclds[ol];
            }
        }
    }
}

extern "C" void kernel_launch(void* const* d_in, const int* in_sizes, int n_in,
                              void* d_out, int out_size, void* d_ws, size_t ws_size,
                              hipStream_t stream) {
    const float* x     = (const float*)d_in[0];  // [16,512,32,32]
    const float* style = (const float*)d_in[1];  // [16,512]
    const float* aw    = (const float*)d_in[2];  // [512,512]
    const float* ab    = (const float*)d_in[3];  // [512]
    const float* cw    = (const float*)d_in[4];  // [512,512,3,3]
    float* out = (float*)d_out;

    char* ws = (char*)d_ws;
    float* s_buf          = (float*)(ws);                      //  32 KB
    float* scl            = (float*)(ws + 32768);              //  32 KB
    float* wsq            = (float*)(ws + 65536);              //   1 MB
    unsigned short* w_t   = (unsigned short*)(ws + 1114112);   // 4.5 MB bf16
    unsigned short* x_pad = (unsigned short*)(ws + 5832704);   // 18.9 MB bf16
    // total ws need: 24,772,608 B

    prep1<<<dim3(3072), 256, 0, stream>>>(cw, style, aw, ab, w_t, wsq, s_buf);
    compute_scale<<<dim3(128, 16), 256, 0, stream>>>(s_buf, wsq, scl);
    build_xpad<<<dim3(8, 34, 16), 256, 0, stream>>>(x, s_buf, x_pad);
    conv_mfma<<<dim3(512), 256, 0, stream>>>(w_t, x_pad, scl, out);
}

// Round 6
// 190.082 us; speedup vs baseline: 1.1389x; 1.0171x over previous
//
#include <hip/hip_runtime.h>

// ModulatedConv2d: B=16, IN=512, OUT=512, STYLE=512, K=3, H=W=32
// out[b,o] = scale[b,o] * conv2d(x[b,i]*s[b,i], W[o,i])   (shared weights!)
// Conv as implicit GEMM (bf16 MFMA, fp32 accum): M=512 out-ch, N=1024 px/batch,
// K = 9 offsets x 512 ch. x staged as zero-padded NHWC bf16 -> no masking.
//
// R2: LDS bank conflicts fully hidden (swizzle fix cost time) -> unswizzled.
// R3: XCD grid swizzle: FETCH 300->28MB. Conv is barrier/vmcnt-drain
//     latency-bound (MfmaUtil 30%, nothing saturated).
// R4: fused-scale b-range bug (b only 0..3). R5: fixed, but BK=64 conv showed
//     INTERMITTENT post-timing divergence (first launch right, replays wrong)
//     => HW race suspected in 8-deep outstanding global_load_lds staging.
//     BK=64 is banned. R6: conv reverted to the R3-proven BK=32 structure;
//     prep2 fusion kept (fixed). Single-variable isolation.

#define BATCH   16
#define CIN     512
#define COUT    512
#define IMG     32
#define PAD_IMG 34

static constexpr float AFF_SCALE = 0.044194173824159216f;  // 1/sqrt(512)
static constexpr float W_SCALE   = 0.014731391274719739f;  // 1/sqrt(512*9)

typedef __bf16 bf16x8 __attribute__((ext_vector_type(8)));
typedef float  f32x4  __attribute__((ext_vector_type(4)));

__device__ inline unsigned short f2bf(float f) {
    union { float f; unsigned int u; } v; v.f = f;
    unsigned int u = v.u;
    unsigned int r = (u + 0x7FFFu + ((u >> 16) & 1u)) >> 16;
    return (unsigned short)r;
}

__device__ inline float waveReduceSum(float v) {
    #pragma unroll
    for (int off = 32; off > 0; off >>= 1) v += __shfl_xor(v, off, 64);
    return v;
}

// ---- kernel 1: fused prep ----
// blocks 0..1023:   repack_w  (wsq[o,i], w_t[e][o][i] bf16)
// blocks 1024..3071: compute_s (s[b,i])
__global__ void prep1(const float* __restrict__ cw,
                      const float* __restrict__ style,
                      const float* __restrict__ aw,
                      const float* __restrict__ ab,
                      unsigned short* __restrict__ w_t,
                      float* __restrict__ wsq,
                      float* __restrict__ s_out) {
    const int tid = threadIdx.x;
    if (blockIdx.x < 1024) {
        __shared__ float wl[2304];
        const float* src = cw + (size_t)blockIdx.x * 2304;
        for (int j = tid; j < 2304; j += 256) wl[j] = src[j];
        __syncthreads();
        const int idx = blockIdx.x * 256 + tid;       // o*512 + i
        const int base = tid * 9;
        float acc = 0.f;
        #pragma unroll
        for (int e = 0; e < 9; ++e) {
            float v = wl[base + e];
            acc += v * v;
            w_t[e * (COUT * CIN) + idx] = f2bf(v);
        }
        wsq[idx] = acc;
    } else {
        const int q = blockIdx.x - 1024;              // 0..2047
        const int b = q >> 7;
        const int i = (q & 127) * 4 + (tid >> 6);
        const int lane = tid & 63;
        float sum = 0.f;
        #pragma unroll
        for (int k = 0; k < 512; k += 64)
            sum += style[b * 512 + k + lane] * aw[i * 512 + k + lane];
        sum = waveReduceSum(sum);
        if (lane == 0)
            s_out[b * 512 + i] = sum * AFF_SCALE + ab[i] + 1.0f;
    }
}

// ---- kernel 2: fused xpad + scale ----
// blocks 0..4351:    x_pad[b][hh][ww][c] = bf16(x[b][c][hh-1][ww-1]*s[b][c])
// blocks 4352..6399: scale[b,o] -- 2048 blocks (b=q>>7 spans 0..15), 1 wave/(b,o)
__global__ void prep2(const float* __restrict__ x,
                      const float* __restrict__ s_in,
                      const float* __restrict__ wsq,
                      unsigned short* __restrict__ xpad,
                      float* __restrict__ scl) {
    const int tid = threadIdx.x;
    if (blockIdx.x >= 4352) {
        const int q = blockIdx.x - 4352;              // 0..2047
        const int b = q >> 7;                         // 0..15
        const int o = (q & 127) * 4 + (tid >> 6);     // 0..511
        const int lane = tid & 63;
        float sum = 0.f;
        #pragma unroll
        for (int i = 0; i < 512; i += 64) {
            float sv = s_in[b * 512 + i + lane];
            sum += sv * sv * wsq[o * 512 + i + lane];
        }
        sum = waveReduceSum(sum);
        if (lane == 0)
            scl[b * 512 + o] = W_SCALE * rsqrtf(W_SCALE * W_SCALE * sum + 1e-8f);
        return;
    }
    const int c0   = blockIdx.x & 7;                  // *64 channels
    const int rest = blockIdx.x >> 3;                 // 0..543
    const int hh   = rest % 34;
    const int b    = rest / 34;
    const int c0b  = c0 * 64;
    unsigned short* rowbase = xpad + (((size_t)b * PAD_IMG + hh) * PAD_IMG) * 512;

    if (hh == 0 || hh == PAD_IMG - 1) {
        for (int j = tid; j < 34 * 32; j += 256) {
            int ww = j >> 5, cp = (j & 31) * 2;
            *(unsigned int*)(rowbase + (size_t)ww * 512 + c0b + cp) = 0u;
        }
        return;
    }

    __shared__ float t[64][33];
    const int h = hh - 1;
    {
        const int wx = tid & 31;
        const int cb = (tid >> 5) * 8;
        const float* xb = x + (((size_t)b * 512 + c0b + cb) * IMG + h) * IMG + wx;
        #pragma unroll
        for (int j = 0; j < 8; ++j)
            t[cb + j][wx] = xb[(size_t)j * (IMG * IMG)] * s_in[b * 512 + c0b + cb + j];
    }
    __syncthreads();
    {
        const int p  = tid >> 3;
        const int cc = (tid & 7) * 8;
        unsigned short* dst = rowbase + (size_t)(p + 1) * 512 + c0b + cc;
        uint4 pk;
        pk.x = (unsigned)f2bf(t[cc + 0][p]) | ((unsigned)f2bf(t[cc + 1][p]) << 16);
        pk.y = (unsigned)f2bf(t[cc + 2][p]) | ((unsigned)f2bf(t[cc + 3][p]) << 16);
        pk.z = (unsigned)f2bf(t[cc + 4][p]) | ((unsigned)f2bf(t[cc + 5][p]) << 16);
        pk.w = (unsigned)f2bf(t[cc + 6][p]) | ((unsigned)f2bf(t[cc + 7][p]) << 16);
        *(uint4*)dst = pk;
    }
    if (tid < 64) {
        int ww = (tid >> 5) ? (PAD_IMG - 1) : 0;
        int cp = (tid & 31) * 2;
        *(unsigned int*)(rowbase + (size_t)ww * 512 + c0b + cp) = 0u;
    }
}

// ---- kernel 3: implicit-GEMM conv, 128x128 tile, BK=32, bf16 MFMA ----
// (exact R3-proven structure: 2+2 staging rounds, 4 outstanding LDS-DMA)
// grid 512 (1-D, XCD-swizzled), block 256 (4 waves, 64x64 each)
__global__ __launch_bounds__(256, 2) void conv_mfma(
    const unsigned short* __restrict__ wt,    // [9][512][512] bf16
    const unsigned short* __restrict__ xpad,  // [16][34][34][512] bf16
    const float* __restrict__ scl,            // [16][512]
    float* __restrict__ out)                  // [16][512][32][32]
{
    __shared__ unsigned short Alds[128 * 32];
    __shared__ unsigned short Blds[128 * 32];
    __shared__ float sclds[128];

    const int tid = threadIdx.x;
    // XCD swizzle: id&7 -> XCD. Each XCD: 16 (h,b)-pairs x 4 m-blocks.
    const int id    = blockIdx.x;
    const int xcd   = id & 7;
    const int local = id >> 3;                   // 0..63
    const int gp    = xcd * 16 + (local >> 2);   // 0..127  (h,b) pair
    const int m0  = (local & 3) * 128;
    const int h0  = (gp & 7) * 4;
    const int b   = gp >> 3;

    if (tid < 128) sclds[tid] = scl[b * 512 + m0 + tid];

    const int wid  = tid >> 6;
    const int lane = tid & 63;
    const int wm = wid & 1, wn = wid >> 1;

    const f32x4 vzero = {0.f, 0.f, 0.f, 0.f};
    f32x4 acc[4][4];
    #pragma unroll
    for (int i = 0; i < 4; ++i)
        #pragma unroll
        for (int j = 0; j < 4; ++j) acc[i][j] = vzero;

    int aOff[2], bOff[2], ldsBase[2];
    #pragma unroll
    for (int r = 0; r < 2; ++r) {
        int f   = r * 256 + tid;       // flat 16B-chunk id
        int row = f >> 2;              // tile row (0..127)
        int col = (f & 3) * 8;         // bf16 offset within 32-wide K
        aOff[r] = row * 512 + col;
        bOff[r] = ((row >> 5) * PAD_IMG + (row & 31)) * 512 + col;
        ldsBase[r] = (r * 256 + wid * 64) * 8;     // wave-uniform dest
    }

    const int arow = (wm * 64 + (lane & 15)) * 32 + (lane >> 4) * 8;
    const int brow = (wn * 64 + (lane & 15)) * 32 + (lane >> 4) * 8;

    for (int e = 0; e < 9; ++e) {
        const int kh = e / 3, kw = e % 3;
        const unsigned short* Abase = wt + (size_t)e * (COUT * CIN) + (size_t)m0 * 512;
        const unsigned short* Bbase =
            xpad + (((size_t)b * PAD_IMG + h0 + kh) * PAD_IMG + kw) * 512;
        for (int kc = 0; kc < 512; kc += 32) {
            __syncthreads();
            #pragma unroll
            for (int r = 0; r < 2; ++r)
                __builtin_amdgcn_global_load_lds(
                    (const __attribute__((address_space(1))) void*)(Abase + aOff[r] + kc),
                    (__attribute__((address_space(3))) void*)(&Alds[ldsBase[r]]),
                    16, 0, 0);
            #pragma unroll
            for (int r = 0; r < 2; ++r)
                __builtin_amdgcn_global_load_lds(
                    (const __attribute__((address_space(1))) void*)(Bbase + bOff[r] + kc),
                    (__attribute__((address_space(3))) void*)(&Blds[ldsBase[r]]),
                    16, 0, 0);
            __syncthreads();

            bf16x8 af[4], bfr[4];
            #pragma unroll
            for (int mi = 0; mi < 4; ++mi)
                af[mi] = *(const bf16x8*)(&Alds[arow + mi * 16 * 32]);
            #pragma unroll
            for (int ni = 0; ni < 4; ++ni)
                bfr[ni] = *(const bf16x8*)(&Blds[brow + ni * 16 * 32]);
            #pragma unroll
            for (int mi = 0; mi < 4; ++mi)
                #pragma unroll
                for (int ni = 0; ni < 4; ++ni)
                    acc[mi][ni] = __builtin_amdgcn_mfma_f32_16x16x32_bf16(
                        af[mi], bfr[ni], acc[mi][ni], 0, 0, 0);
        }
    }

    // epilogue: C[m][n] layout col=lane&15, row=(lane>>4)*4+reg  [m89-verified]
    const int colp = lane & 15;
    const int rowq = (lane >> 4) * 4;
    const int p0 = h0 * 32;
    #pragma unroll
    for (int mi = 0; mi < 4; ++mi) {
        #pragma unroll
        for (int ni = 0; ni < 4; ++ni) {
            const int p = p0 + wn * 64 + ni * 16 + colp;
            #pragma unroll
            for (int r2 = 0; r2 < 4; ++r2) {
                const int ol = wm * 64 + mi * 16 + rowq + r2;
                out[(((size_t)b * 512 + m0 + ol) << 10) + p] =
                    acc[mi][ni][r2] * sclds[ol];
            }
        }
    }
}

extern "C" void kernel_launch(void* const* d_in, const int* in_sizes, int n_in,
                              void* d_out, int out_size, void* d_ws, size_t ws_size,
                              hipStream_t stream) {
    const float* x     = (const float*)d_in[0];  // [16,512,32,32]
    const float* style = (const float*)d_in[1];  // [16,512]
    const float* aw    = (const float*)d_in[2];  // [512,512]
    const float* ab    = (const float*)d_in[3];  // [512]
    const float* cw    = (const float*)d_in[4];  // [512,512,3,3]
    float* out = (float*)d_out;

    char* ws = (char*)d_ws;
    float* s_buf          = (float*)(ws);                      //  32 KB
    float* scl            = (float*)(ws + 32768);              //  32 KB
    float* wsq            = (float*)(ws + 65536);              //   1 MB
    unsigned short* w_t   = (unsigned short*)(ws + 1114112);   // 4.5 MB bf16
    unsigned short* x_pad = (unsigned short*)(ws + 5832704);   // 18.9 MB bf16
    // total ws need: 24,772,608 B

    prep1<<<dim3(3072), 256, 0, stream>>>(cw, style, aw, ab, w_t, wsq, s_buf);
    prep2<<<dim3(6400), 256, 0, stream>>>(x, s_buf, wsq, x_pad, scl);
    conv_mfma<<<dim3(512), 256, 0, stream>>>(w_t, x_pad, scl, out);
}